// Round 3
// baseline (239.724 us; speedup 1.0000x reference)
//
#include <hip/hip_runtime.h>
#include <hip/hip_bf16.h>

// ENN — R8: 2 launches. Key insight: H has only VOCAB=20 distinct rows, so
// P3_j = T2[cat_j] (20x64 table) and preI_i = T1[cat_i] — built per-block in LDS.
// k_pre0: zero Vpart/done/out + build i-independent We2 hi/lo B-frags + bias fold.
// k_fused (grid 2048, block = i*2+half): per-block T2/preI build; main MFMA loop
//   reads A-operand inputs via ds_read_b128 gather from T2 (rows padded to 68);
//   second-finishing block per atom i (atomic election) runs diag+epilogue in-kernel.

#define N_ATOMS 1024
#define L_DIM 64
#define CSCALE 2.8853900817779268f   // 2*log2(e)
#define T2LD 68                      // T2 row stride (floats): 16B-aligned, bank offset 4

typedef _Float16 f16x8 __attribute__((ext_vector_type(8)));
typedef __fp16  fp16x2 __attribute__((ext_vector_type(2)));
typedef float f32x4 __attribute__((ext_vector_type(4)));

__device__ __forceinline__ float tanh_fast(float x) {
    float e = __builtin_amdgcn_exp2f(x * CSCALE);
    float r = __builtin_amdgcn_rcpf(e + 1.0f);
    return fmaf(-2.0f, r, 1.0f);
}

// ---------------- Stage 0: zero + i-independent tables ----------------
__global__ __launch_bounds__(256) void k_pre0(const float* __restrict__ We2,
                                              const float* __restrict__ be2,
                                              f16x8* __restrict__ bHg,
                                              f16x8* __restrict__ bLg,
                                              float* __restrict__ biasg,
                                              float* __restrict__ Vpart,
                                              int* __restrict__ done,
                                              float* __restrict__ out) {
    int t = threadIdx.x;
    if (blockIdx.x == 0) {
        // B' = -2c*We2 in B-frag order, hi/lo split; bias fold = c*(be2 + colsum(We2)).
        int nt = t >> 6;          // 0..3
        int lane = t & 63;
        int q2 = lane >> 4, nl2 = lane & 15;
        float psum = 0.f;
#pragma unroll
        for (int kt = 0; kt < 2; kt++) {
            f16x8 hi8, lo8;
#pragma unroll
            for (int e = 0; e < 8; e++) {
                float x = We2[(kt * 32 + q2 * 8 + e) * L_DIM + nt * 16 + nl2];
                psum += x;
                float wp = -2.0f * CSCALE * x;
                _Float16 hi = (_Float16)wp;
                hi8[e] = hi;
                lo8[e] = (_Float16)(wp - (float)hi);
            }
            bHg[(kt * 4 + nt) * 64 + lane] = hi8;
            bLg[(kt * 4 + nt) * 64 + lane] = lo8;
        }
        psum += __shfl_xor(psum, 16);
        psum += __shfl_xor(psum, 32);
        biasg[lane * 4 + nt] = CSCALE * (be2[nt * 16 + nl2] + psum);
        if (t == 0) out[0] = 0.f;
    } else {
        int idx = (blockIdx.x - 1) * 256 + t;   // 0..2047
        if (idx < N_ATOMS) Vpart[idx] = 0.f;
        else done[idx - N_ATOMS] = 0;
    }
}

// ---------------- Stage 1: fused main (grid 2048: i = bid>>1, half = bid&1) ----------------
__global__ __launch_bounds__(256) void k_fused(const int* __restrict__ cat,
                                               const float* __restrict__ Z,
                                               const float* __restrict__ LM,
                                               const float* __restrict__ We1,
                                               const float* __restrict__ be1,
                                               const float* __restrict__ We2,
                                               const float* __restrict__ be2,
                                               const f16x8* __restrict__ bHg,
                                               const f16x8* __restrict__ bLg,
                                               const float* __restrict__ biasg,
                                               const float* __restrict__ Wh1,
                                               const float* __restrict__ bh1,
                                               const float* __restrict__ Wh2,
                                               const float* __restrict__ bh2,
                                               const float* __restrict__ Wo,
                                               const float* __restrict__ bo,
                                               float* __restrict__ Vpart,
                                               int* __restrict__ done,
                                               float* __restrict__ out) {
    int bid = blockIdx.x;
    int i = bid >> 1, half = bid & 1;
    int t = threadIdx.x;
    int lane = t & 63;
    int wave = t >> 6;          // 0..3
    int nlo = lane & 15;
    int quad = lane >> 4;

    __shared__ float d2s[512];
    __shared__ float red[256];
    __shared__ f16x8 bLs[8 * 64];        // 8 KB
    __shared__ float T2s[20 * T2LD];     // c*(LM@W1j + be1), padded rows
    __shared__ float preIs[L_DIM];       // c*(LM[cat_i]@W1i)
    __shared__ int   cats[512];
    __shared__ float dgt[L_DIM];
    __shared__ float hhs[L_DIM];
    __shared__ float RallS;
    __shared__ int   winflag;

    // cats + d2 for this i, this half of j
    float zi0 = Z[i * 3], zi1 = Z[i * 3 + 1], zi2 = Z[i * 3 + 2];
    for (int p = t; p < 512; p += 256) {
        int j = half * 512 + p;
        cats[p] = cat[j];
        float a = zi0 - Z[j * 3], b = zi1 - Z[j * 3 + 1], c = zi2 - Z[j * 3 + 2];
        d2s[p] = a * a + b * b + c * c;
    }

    // T2 table: wave handles rows {wave, wave+4, ..., wave+16}; c is wave-uniform.
#pragma unroll
    for (int r = 0; r < 5; r++) {
        int c = wave + 4 * r;
        float s = 0.f;
#pragma unroll
        for (int m = 0; m < L_DIM; m++)
            s = fmaf(LM[c * L_DIM + m], We1[(L_DIM + m) * L_DIM + lane], s);
        T2s[c * T2LD + lane] = (s + be1[lane]) * CSCALE;
    }
    // preI row for atom i (wave 0)
    int ci = cat[i];
    if (t < 64) {
        float s = 0.f;
#pragma unroll
        for (int m = 0; m < L_DIM; m++)
            s = fmaf(LM[ci * L_DIM + m], We1[m * L_DIM + t], s);
        preIs[t] = s * CSCALE;
    }

    // B fragments from precomputed tables: hi to regs, lo to LDS (cooperative)
    f16x8 bH[4][2];
#pragma unroll
    for (int nt = 0; nt < 4; nt++) {
        bH[nt][0] = bHg[(0 * 4 + nt) * 64 + lane];
        bH[nt][1] = bHg[(1 * 4 + nt) * 64 + lane];
    }
#pragma unroll
    for (int idx = 0; idx < 2; idx++) {
        int e = wave + idx * 4;
        bLs[e * 64 + lane] = bLg[e * 64 + lane];
    }
    f32x4 bias4 = *(const f32x4*)(biasg + lane * 4);

    // per-lane m-block bases + wz
    int mbs[4];
    f32x4 wzR[4];
#pragma unroll
    for (int g = 0; g < 4; g++) {
        int mb = ((g >> 1) << 5) + (quad << 3) + ((g & 1) << 2);
        mbs[g] = mb;
        f32x4 wz = *(const f32x4*)(We1 + 2 * L_DIM * L_DIM + mb);
        wzR[g] = wz * CSCALE;
    }

    __syncthreads();

    f32x4 aiR[4];
#pragma unroll
    for (int g = 0; g < 4; g++) aiR[g] = *(const f32x4*)(preIs + mbs[g]);

    // p for k=0: T2 gather + aiR fold
    {
        int sc = cats[(wave * 8 + 0) * 16 + nlo];
        const float* Tr = T2s + sc * T2LD;
        // loads issued below via p0..p3 init
        (void)Tr;
    }
    int sc0 = cats[(wave * 8) * 16 + nlo];
    const float* Tr0 = T2s + sc0 * T2LD;
    f32x4 p0 = *(const f32x4*)(Tr0 + mbs[0]) + aiR[0];
    f32x4 p1 = *(const f32x4*)(Tr0 + mbs[1]) + aiR[1];
    f32x4 p2 = *(const f32x4*)(Tr0 + mbs[2]) + aiR[2];
    f32x4 p3 = *(const f32x4*)(Tr0 + mbs[3]) + aiR[3];

    f32x4 Vr4 = {0.f, 0.f, 0.f, 0.f};   // sum over this half's j,l of 1/(exp2(S')+1)
    for (int k = 0; k < 8; k++) {
        float d2 = d2s[(wave * 8 + k) * 16 + nlo];
        f32x4 d2v = {d2, d2, d2, d2};

        // A-frag: r = 1/(exp2(z)+1) per element
        f32x4 z0 = p0 + d2v * wzR[0];
        f32x4 z1 = p1 + d2v * wzR[1];
        f32x4 z2 = p2 + d2v * wzR[2];
        f32x4 z3 = p3 + d2v * wzR[3];
        f32x4 ex0, ex1, ex2, ex3;
#pragma unroll
        for (int e = 0; e < 4; e++) {
            ex0[e] = __builtin_amdgcn_exp2f(z0[e]);
            ex1[e] = __builtin_amdgcn_exp2f(z1[e]);
            ex2[e] = __builtin_amdgcn_exp2f(z2[e]);
            ex3[e] = __builtin_amdgcn_exp2f(z3[e]);
        }
        ex0 += 1.0f; ex1 += 1.0f; ex2 += 1.0f; ex3 += 1.0f;
        f32x4 r0, r1, r2, r3;
#pragma unroll
        for (int e = 0; e < 4; e++) {
            r0[e] = __builtin_amdgcn_rcpf(ex0[e]);
            r1[e] = __builtin_amdgcn_rcpf(ex1[e]);
            r2[e] = __builtin_amdgcn_rcpf(ex2[e]);
            r3[e] = __builtin_amdgcn_rcpf(ex3[e]);
        }
        union { f16x8 v; fp16x2 h2[4]; } u0, u1;
        u0.h2[0] = __builtin_amdgcn_cvt_pkrtz(r0[0], r0[1]);
        u0.h2[1] = __builtin_amdgcn_cvt_pkrtz(r0[2], r0[3]);
        u0.h2[2] = __builtin_amdgcn_cvt_pkrtz(r1[0], r1[1]);
        u0.h2[3] = __builtin_amdgcn_cvt_pkrtz(r1[2], r1[3]);
        u1.h2[0] = __builtin_amdgcn_cvt_pkrtz(r2[0], r2[1]);
        u1.h2[1] = __builtin_amdgcn_cvt_pkrtz(r2[2], r2[3]);
        u1.h2[2] = __builtin_amdgcn_cvt_pkrtz(r3[0], r3[1]);
        u1.h2[3] = __builtin_amdgcn_cvt_pkrtz(r3[2], r3[3]);
        f16x8 aH0 = u0.v, aH1 = u1.v;

        if (k < 7) {
            int sc = cats[(wave * 8 + k + 1) * 16 + nlo];
            const float* Tr = T2s + sc * T2LD;
            p0 = *(const f32x4*)(Tr + mbs[0]) + aiR[0];
            p1 = *(const f32x4*)(Tr + mbs[1]) + aiR[1];
            p2 = *(const f32x4*)(Tr + mbs[2]) + aiR[2];
            p3 = *(const f32x4*)(Tr + mbs[3]) + aiR[3];
        }

#pragma unroll
        for (int nt = 0; nt < 4; nt++) {
            f16x8 bl0 = bLs[(0 * 4 + nt) * 64 + lane];
            f16x8 bl1 = bLs[(1 * 4 + nt) * 64 + lane];
            f32x4 acc = {bias4[nt], bias4[nt], bias4[nt], bias4[nt]};
            acc = __builtin_amdgcn_mfma_f32_16x16x32_f16(aH0, bH[nt][0], acc, 0, 0, 0);
            acc = __builtin_amdgcn_mfma_f32_16x16x32_f16(aH0, bl0, acc, 0, 0, 0);
            acc = __builtin_amdgcn_mfma_f32_16x16x32_f16(aH1, bH[nt][1], acc, 0, 0, 0);
            acc = __builtin_amdgcn_mfma_f32_16x16x32_f16(aH1, bl1, acc, 0, 0, 0);
            f32x4 ev;
#pragma unroll
            for (int r4 = 0; r4 < 4; r4++) ev[r4] = __builtin_amdgcn_exp2f(acc[r4]);
            ev += 1.0f;
            f32x4 rv;
#pragma unroll
            for (int r4 = 0; r4 < 4; r4++) rv[r4] = __builtin_amdgcn_rcpf(ev[r4]);
            Vr4 += rv;
        }
    }

    red[t] = Vr4[0] + Vr4[1] + Vr4[2] + Vr4[3];
    __syncthreads();

    // partial reduce + last-block election
    if (t < 64) {
        float r = red[t] + red[t + 64] + red[t + 128] + red[t + 192];
#pragma unroll
        for (int o = 32; o > 0; o >>= 1) r += __shfl_xor(r, o);
        if (t == 0) {
            atomicAdd(Vpart + i, r);
            __threadfence();
            int old = atomicAdd(done + i, 1);
            if (old == 1) {
                __threadfence();
                RallS = atomicAdd(Vpart + i, 0.0f);   // coherent final read
                winflag = 1;
            } else {
                winflag = 0;
            }
        }
    }
    __syncthreads();

    if (winflag) {
        // ---- diagonal + epilogue for atom i (second-finishing block) ----
        if (t < 64) {
            float z = preIs[t] + T2s[ci * T2LD + t];   // d2 = 0 on diagonal
            float rr = __builtin_amdgcn_rcpf(__builtin_amdgcn_exp2f(z) + 1.0f);
            dgt[t] = fmaf(-2.0f, rr, 1.0f);
        }
        __syncthreads();
        if (t < 64) {
            float S = be2[t];
#pragma unroll
            for (int m = 0; m < L_DIM; m++) S = fmaf(dgt[m], We2[m * L_DIM + t], S);
            float rd = __builtin_amdgcn_rcpf(__builtin_amdgcn_exp2f(S * CSCALE) + 1.0f);
#pragma unroll
            for (int o = 32; o > 0; o >>= 1) rd += __shfl_xor(rd, o);
            float V = fmaf(-2.0f, RallS - rd, (float)(1023 * L_DIM));
            float s = 0.f;
#pragma unroll
            for (int m = 0; m < L_DIM; m++) s = fmaf(LM[ci * L_DIM + m], Wh1[m * L_DIM + t], s);
            s = fmaf(V, Wh1[L_DIM * L_DIM + t], s) + bh1[t];
            hhs[t] = tanh_fast(s);
        }
        __syncthreads();
        if (t < 64) {
            float s2 = 0.f;
#pragma unroll
            for (int m = 0; m < L_DIM; m++) s2 = fmaf(hhs[m], Wh2[m * L_DIM + t], s2);
            float nh = tanh_fast(s2 + bh2[t]);
            float w = nh * Wo[t];
#pragma unroll
            for (int o = 32; o > 0; o >>= 1) w += __shfl_down(w, o);
            if (t == 0) atomicAdd(out, w + (i == 0 ? bo[0] : 0.f));
        }
    }
}

extern "C" void kernel_launch(void* const* d_in, const int* in_sizes, int n_in,
                              void* d_out, int out_size, void* d_ws, size_t ws_size,
                              hipStream_t stream) {
    const int*   cat = (const int*)  d_in[0];
    const float* Z   = (const float*)d_in[1];
    const float* LM  = (const float*)d_in[2];
    const float* We1 = (const float*)d_in[3];
    const float* be1 = (const float*)d_in[4];
    const float* We2 = (const float*)d_in[5];
    const float* be2 = (const float*)d_in[6];
    const float* Wh1 = (const float*)d_in[7];
    const float* bh1 = (const float*)d_in[8];
    const float* Wh2 = (const float*)d_in[9];
    const float* bh2 = (const float*)d_in[10];
    const float* Wo  = (const float*)d_in[11];
    const float* bo  = (const float*)d_in[12];
    float* out = (float*)d_out;

    float* ws    = (float*)d_ws;
    float* Vpart = ws;                        // 1024 floats
    int*   done  = (int*)(ws + N_ATOMS);      // 1024 ints
    float* biasg = ws + 2 * N_ATOMS;          // 256 floats
    f16x8* bHg   = (f16x8*)(ws + 2 * N_ATOMS + 256);   // 512 * f16x8 = 8 KB
    f16x8* bLg   = bHg + 8 * 64;                        // 8 KB

    k_pre0<<<9, 256, 0, stream>>>(We2, be2, bHg, bLg, biasg, Vpart, done, out);
    k_fused<<<N_ATOMS * 2, 256, 0, stream>>>(cat, Z, LM, We1, be1, We2, be2,
                                             bHg, bLg, biasg,
                                             Wh1, bh1, Wh2, bh2, Wo, bo,
                                             Vpart, done, out);
}

// Round 4
// 150.841 us; speedup vs baseline: 1.5892x; 1.5892x over previous
//
#include <hip/hip_runtime.h>
#include <hip/hip_bf16.h>

// ENN — R9: controlled A/B. k_prep + k_main are R7's measured-good versions
// (k_main 41.7 µs, zero LDS conflicts). ONE change kept from R8: in-kernel
// election epilogue (2 launches instead of 3). R8's per-block T2 rebuild and
// LDS gather (the 4x regression: 1.37M bank conflicts, 170M redundant FMA)
// are fully reverted.
//
// k_prep: H = LM[cat]; preI = c*(H@W1i); P3 = pack(c*(H@W1j + be1));
//         block0: bHg/bLg (hi/lo of -2c*We2, B-frag order) + biasg (colsum fold);
//         zero out/Vpart/done.
// k_main (grid 2048, block = i*2+half): 8 j-chunks of 16 per wave;
//   r = 1/(exp2(z)+1); S' = bias + r @ (-2c*We2) via f16 MFMA (hi/lo);
//   atomicAdd(Vpart[i]); second-finishing block per atom runs diag+epilogue.

#define N_ATOMS 1024
#define L_DIM 64
#define CSCALE 2.8853900817779268f   // 2*log2(e)

typedef _Float16 f16x8 __attribute__((ext_vector_type(8)));
typedef __fp16  fp16x2 __attribute__((ext_vector_type(2)));
typedef float f32x4 __attribute__((ext_vector_type(4)));

__device__ __forceinline__ float tanh_fast(float x) {
    float e = __builtin_amdgcn_exp2f(x * CSCALE);
    float r = __builtin_amdgcn_rcpf(e + 1.0f);
    return fmaf(-2.0f, r, 1.0f);
}

// ---------------- Stage 1: prep ----------------
__global__ __launch_bounds__(256) void k_prep(const int* __restrict__ cat,
                                              const float* __restrict__ LM,
                                              const float* __restrict__ We1,
                                              const float* __restrict__ be1,
                                              const float* __restrict__ We2,
                                              const float* __restrict__ be2,
                                              float* __restrict__ H,
                                              float* __restrict__ preI,
                                              float* __restrict__ P3,
                                              float* __restrict__ Vpart,
                                              int* __restrict__ done,
                                              f16x8* __restrict__ bHg,
                                              f16x8* __restrict__ bLg,
                                              float* __restrict__ biasg,
                                              float* __restrict__ out) {
    int t = threadIdx.x;
    int sub = t >> 6, l = t & 63;
    int i = blockIdx.x * 4 + sub;
    if (blockIdx.x == 0 && t == 0) out[0] = 0.f;
    if (t < 4) {
        Vpart[blockIdx.x * 4 + t] = 0.f;
        done[blockIdx.x * 4 + t] = 0;
    }
    __shared__ float hrow[4][L_DIM];
    float hv = LM[cat[i] * L_DIM + l];
    hrow[sub][l] = hv;
    H[i * L_DIM + l] = hv;
    __syncthreads();
    float s1 = 0.f, s2 = 0.f;
#pragma unroll
    for (int m = 0; m < L_DIM; m++) {
        float h = hrow[sub][m];
        s1 = fmaf(h, We1[m * L_DIM + l], s1);
        s2 = fmaf(h, We1[(L_DIM + m) * L_DIM + l], s2);
    }
    preI[i * L_DIM + l] = s1 * CSCALE;
    // pack c*(prejb) into A-fragment order (verified R2/R4):
    int cc = i >> 4;
    int Ll = i & 15;
    int quad = (l >> 3) & 3;
    int L = quad * 16 + Ll;
    int g = ((l >> 5) << 1) | ((l >> 2) & 1);
    int e2 = l & 3;
    P3[cc * 1024 + g * 256 + L * 4 + e2] = (s2 + be1[l]) * CSCALE;

    // --- i-independent B-fragment + bias build (once, block 0; wave w <-> nt) ---
    if (blockIdx.x == 0) {
        int nt = t >> 6;          // 0..3
        int lane = t & 63;
        int q2 = lane >> 4, nl2 = lane & 15;
        float psum = 0.f;
#pragma unroll
        for (int kt = 0; kt < 2; kt++) {
            f16x8 hi8, lo8;
#pragma unroll
            for (int e = 0; e < 8; e++) {
                float x = We2[(kt * 32 + q2 * 8 + e) * L_DIM + nt * 16 + nl2];
                psum += x;
                float wp = -2.0f * CSCALE * x;
                _Float16 hi = (_Float16)wp;
                hi8[e] = hi;
                lo8[e] = (_Float16)(wp - (float)hi);
            }
            bHg[(kt * 4 + nt) * 64 + lane] = hi8;
            bLg[(kt * 4 + nt) * 64 + lane] = lo8;
        }
        psum += __shfl_xor(psum, 16);
        psum += __shfl_xor(psum, 32);
        biasg[lane * 4 + nt] = CSCALE * (be2[nt * 16 + nl2] + psum);
    }
}

// ---------------- Stage 2: fused main (grid 2048: i = bid>>1, half = bid&1) ----------------
__global__ __launch_bounds__(256) void k_main(const float* __restrict__ Z,
                                              const float* __restrict__ We1,
                                              const float* __restrict__ preI,
                                              const float* __restrict__ P3,
                                              const f16x8* __restrict__ bHg,
                                              const f16x8* __restrict__ bLg,
                                              const float* __restrict__ biasg,
                                              const float* __restrict__ H,
                                              const float* __restrict__ We2,
                                              const float* __restrict__ be2,
                                              const float* __restrict__ Wh1,
                                              const float* __restrict__ bh1,
                                              const float* __restrict__ Wh2,
                                              const float* __restrict__ bh2,
                                              const float* __restrict__ Wo,
                                              const float* __restrict__ bo,
                                              float* __restrict__ Vpart,
                                              int* __restrict__ done,
                                              float* __restrict__ out) {
    int bid = blockIdx.x;
    int i = bid >> 1, half = bid & 1;
    int t = threadIdx.x;
    int lane = t & 63;
    int wave = t >> 6;          // 0..3
    int nlo = lane & 15;
    int quad = lane >> 4;

    __shared__ float d2s[512];
    __shared__ float red[256];
    __shared__ f16x8 bLs[8 * 64];   // 8 KB
    __shared__ float dgt[L_DIM];
    __shared__ float hrow_s[L_DIM];
    __shared__ float hhs[L_DIM];
    __shared__ float RallS;
    __shared__ int   winflag;

    // d2 table for this i, this half of j
    float zi0 = Z[i * 3], zi1 = Z[i * 3 + 1], zi2 = Z[i * 3 + 2];
    for (int p = t; p < 512; p += 256) {
        int j = half * 512 + p;
        float a = zi0 - Z[j * 3], b = zi1 - Z[j * 3 + 1], c = zi2 - Z[j * 3 + 2];
        d2s[p] = a * a + b * b + c * c;
    }

    // per-lane constants
    f32x4 aiR[4], wzR[4];
#pragma unroll
    for (int g = 0; g < 4; g++) {
        int mb = ((g >> 1) << 5) + (quad << 3) + ((g & 1) << 2);
        aiR[g] = *(const f32x4*)(preI + i * L_DIM + mb);
        f32x4 wz = *(const f32x4*)(We1 + 2 * L_DIM * L_DIM + mb);
        wzR[g] = wz * CSCALE;
    }

    // B fragments from precomputed tables: hi to regs, lo to LDS (cooperative)
    f16x8 bH[4][2];
#pragma unroll
    for (int nt = 0; nt < 4; nt++) {
        bH[nt][0] = bHg[(0 * 4 + nt) * 64 + lane];
        bH[nt][1] = bHg[(1 * 4 + nt) * 64 + lane];
    }
#pragma unroll
    for (int idx = 0; idx < 2; idx++) {
        int e = wave + idx * 4;
        bLs[e * 64 + lane] = bLg[e * 64 + lane];
    }
    f32x4 bias4 = *(const f32x4*)(biasg + lane * 4);

    // 8 chunks of 16 j per wave; aiR folded into the p registers.
    const float* Pbase = P3 + (half * 32 + wave * 8) * 1024 + lane * 4;
    f32x4 p0 = *(const f32x4*)(Pbase + 0 * 256) + aiR[0];
    f32x4 p1 = *(const f32x4*)(Pbase + 1 * 256) + aiR[1];
    f32x4 p2 = *(const f32x4*)(Pbase + 2 * 256) + aiR[2];
    f32x4 p3 = *(const f32x4*)(Pbase + 3 * 256) + aiR[3];

    __syncthreads();

    f32x4 Vr4 = {0.f, 0.f, 0.f, 0.f};   // sum over this half's j,l of 1/(exp2(S')+1)
    for (int k = 0; k < 8; k++) {
        float d2 = d2s[(wave * 8 + k) * 16 + nlo];
        f32x4 d2v = {d2, d2, d2, d2};

        // A-frag: r = 1/(exp2(z)+1) per element
        f32x4 z0 = p0 + d2v * wzR[0];
        f32x4 z1 = p1 + d2v * wzR[1];
        f32x4 z2 = p2 + d2v * wzR[2];
        f32x4 z3 = p3 + d2v * wzR[3];
        f32x4 ex0, ex1, ex2, ex3;
#pragma unroll
        for (int e = 0; e < 4; e++) {
            ex0[e] = __builtin_amdgcn_exp2f(z0[e]);
            ex1[e] = __builtin_amdgcn_exp2f(z1[e]);
            ex2[e] = __builtin_amdgcn_exp2f(z2[e]);
            ex3[e] = __builtin_amdgcn_exp2f(z3[e]);
        }
        ex0 += 1.0f; ex1 += 1.0f; ex2 += 1.0f; ex3 += 1.0f;
        f32x4 r0, r1, r2, r3;
#pragma unroll
        for (int e = 0; e < 4; e++) {
            r0[e] = __builtin_amdgcn_rcpf(ex0[e]);
            r1[e] = __builtin_amdgcn_rcpf(ex1[e]);
            r2[e] = __builtin_amdgcn_rcpf(ex2[e]);
            r3[e] = __builtin_amdgcn_rcpf(ex3[e]);
        }
        union { f16x8 v; fp16x2 h2[4]; } u0, u1;
        u0.h2[0] = __builtin_amdgcn_cvt_pkrtz(r0[0], r0[1]);
        u0.h2[1] = __builtin_amdgcn_cvt_pkrtz(r0[2], r0[3]);
        u0.h2[2] = __builtin_amdgcn_cvt_pkrtz(r1[0], r1[1]);
        u0.h2[3] = __builtin_amdgcn_cvt_pkrtz(r1[2], r1[3]);
        u1.h2[0] = __builtin_amdgcn_cvt_pkrtz(r2[0], r2[1]);
        u1.h2[1] = __builtin_amdgcn_cvt_pkrtz(r2[2], r2[3]);
        u1.h2[2] = __builtin_amdgcn_cvt_pkrtz(r3[0], r3[1]);
        u1.h2[3] = __builtin_amdgcn_cvt_pkrtz(r3[2], r3[3]);
        f16x8 aH0 = u0.v, aH1 = u1.v;

        if (k < 7) {
            const float* nb = Pbase + (k + 1) * 1024;
            p0 = *(const f32x4*)(nb + 0 * 256) + aiR[0];
            p1 = *(const f32x4*)(nb + 1 * 256) + aiR[1];
            p2 = *(const f32x4*)(nb + 2 * 256) + aiR[2];
            p3 = *(const f32x4*)(nb + 3 * 256) + aiR[3];
        }

#pragma unroll
        for (int nt = 0; nt < 4; nt++) {
            f16x8 bl0 = bLs[(0 * 4 + nt) * 64 + lane];
            f16x8 bl1 = bLs[(1 * 4 + nt) * 64 + lane];
            f32x4 acc = {bias4[nt], bias4[nt], bias4[nt], bias4[nt]};
            acc = __builtin_amdgcn_mfma_f32_16x16x32_f16(aH0, bH[nt][0], acc, 0, 0, 0);
            acc = __builtin_amdgcn_mfma_f32_16x16x32_f16(aH0, bl0, acc, 0, 0, 0);
            acc = __builtin_amdgcn_mfma_f32_16x16x32_f16(aH1, bH[nt][1], acc, 0, 0, 0);
            acc = __builtin_amdgcn_mfma_f32_16x16x32_f16(aH1, bl1, acc, 0, 0, 0);
            f32x4 ev;
#pragma unroll
            for (int r4 = 0; r4 < 4; r4++) ev[r4] = __builtin_amdgcn_exp2f(acc[r4]);
            ev += 1.0f;
            f32x4 rv;
#pragma unroll
            for (int r4 = 0; r4 < 4; r4++) rv[r4] = __builtin_amdgcn_rcpf(ev[r4]);
            Vr4 += rv;
        }
    }

    red[t] = Vr4[0] + Vr4[1] + Vr4[2] + Vr4[3];
    __syncthreads();

    // partial reduce + last-block election
    if (t < 64) {
        float r = red[t] + red[t + 64] + red[t + 128] + red[t + 192];
#pragma unroll
        for (int o = 32; o > 0; o >>= 1) r += __shfl_xor(r, o);
        if (t == 0) {
            atomicAdd(Vpart + i, r);
            __threadfence();
            int old = atomicAdd(done + i, 1);
            if (old == 1) {
                RallS = atomicAdd(Vpart + i, 0.0f);   // coherent read of final sum
                winflag = 1;
            } else {
                winflag = 0;
            }
        }
    }
    __syncthreads();

    if (winflag) {
        // ---- diagonal + epilogue for atom i (second-finishing block only) ----
        if (t < 64) {
            // diagonal h1 tanh (d2 = 0), m = t  — packed P3 index (verified R7 k_post)
            int cc = i >> 4, Ll = i & 15;
            int q2 = (t >> 3) & 3;
            int g = ((t >> 5) << 1) | ((t >> 2) & 1);
            float z = preI[i * L_DIM + t] + P3[cc * 1024 + g * 256 + (q2 * 16 + Ll) * 4 + (t & 3)];
            float rr = __builtin_amdgcn_rcpf(__builtin_amdgcn_exp2f(z) + 1.0f);
            dgt[t] = fmaf(-2.0f, rr, 1.0f);
            hrow_s[t] = H[i * L_DIM + t];
        }
        __syncthreads();
        if (t < 64) {
            float S = be2[t];
#pragma unroll
            for (int m = 0; m < L_DIM; m++) S = fmaf(dgt[m], We2[m * L_DIM + t], S);
            float rd = __builtin_amdgcn_rcpf(__builtin_amdgcn_exp2f(S * CSCALE) + 1.0f);
#pragma unroll
            for (int o = 32; o > 0; o >>= 1) rd += __shfl_xor(rd, o);
            float V = fmaf(-2.0f, RallS - rd, (float)(1023 * L_DIM));
            float s = 0.f;
#pragma unroll
            for (int m = 0; m < L_DIM; m++) s = fmaf(hrow_s[m], Wh1[m * L_DIM + t], s);
            s = fmaf(V, Wh1[L_DIM * L_DIM + t], s) + bh1[t];
            hhs[t] = tanh_fast(s);
        }
        __syncthreads();
        if (t < 64) {
            float s2 = 0.f;
#pragma unroll
            for (int m = 0; m < L_DIM; m++) s2 = fmaf(hhs[m], Wh2[m * L_DIM + t], s2);
            float nh = tanh_fast(s2 + bh2[t]);
            float w = nh * Wo[t];
#pragma unroll
            for (int o = 32; o > 0; o >>= 1) w += __shfl_down(w, o);
            if (t == 0) atomicAdd(out, w + (i == 0 ? bo[0] : 0.f));
        }
    }
}

extern "C" void kernel_launch(void* const* d_in, const int* in_sizes, int n_in,
                              void* d_out, int out_size, void* d_ws, size_t ws_size,
                              hipStream_t stream) {
    const int*   cat = (const int*)  d_in[0];
    const float* Z   = (const float*)d_in[1];
    const float* LM  = (const float*)d_in[2];
    const float* We1 = (const float*)d_in[3];
    const float* be1 = (const float*)d_in[4];
    const float* We2 = (const float*)d_in[5];
    const float* be2 = (const float*)d_in[6];
    const float* Wh1 = (const float*)d_in[7];
    const float* bh1 = (const float*)d_in[8];
    const float* Wh2 = (const float*)d_in[9];
    const float* bh2 = (const float*)d_in[10];
    const float* Wo  = (const float*)d_in[11];
    const float* bo  = (const float*)d_in[12];
    float* out = (float*)d_out;

    float* ws    = (float*)d_ws;
    float* H     = ws;                        // 1024*64
    float* preI  = H     + N_ATOMS * L_DIM;   // 1024*64 (c-prescaled)
    float* P3    = preI  + N_ATOMS * L_DIM;   // 1024*64 (packed, c-prescaled)
    float* Vpart = P3    + N_ATOMS * L_DIM;   // 1024
    int*   done  = (int*)(Vpart + N_ATOMS);   // 1024
    float* biasg = (float*)(done + N_ATOMS);  // 256
    f16x8* bHg   = (f16x8*)(biasg + 256);     // 8 KB
    f16x8* bLg   = bHg + 8 * 64;              // 8 KB

    k_prep<<<N_ATOMS / 4, 256, 0, stream>>>(cat, LM, We1, be1, We2, be2,
                                            H, preI, P3, Vpart, done, bHg, bLg, biasg, out);
    k_main<<<N_ATOMS * 2, 256, 0, stream>>>(Z, We1, preI, P3, bHg, bLg, biasg,
                                            H, We2, be2, Wh1, bh1, Wh2, bh2, Wo, bo,
                                            Vpart, done, out);
}

// Round 5
// 121.716 us; speedup vs baseline: 1.9695x; 1.2393x over previous
//
#include <hip/hip_runtime.h>
#include <hip/hip_bf16.h>

// ENN — R10: R9 minus the poison. Election via atomicAdd RETURN VALUE:
// first block for atom i sees old==0.0, second sees old==r_other>0 and computes
// Rall = old + r locally. No __threadfence, no done[] counter, no re-read —
// R9's counters showed the fence caused cache writeback/invalidate churn
// (FETCH 955->1650KB, WRITE 64->192KB, VALUBusy 55->33, k_main 41.7->74.5).
//
// k_prep: H = LM[cat]; preI = c*(H@W1i); P3 = pack(c*(H@W1j + be1));
//         block0: bHg/bLg (hi/lo of -2c*We2, B-frag order) + biasg (colsum fold);
//         zero out/Vpart.
// k_main (grid 2048, block = i*2+half): 8 j-chunks of 16 per wave;
//   r = 1/(exp2(z)+1); S' = bias + r @ (-2c*We2) via f16 MFMA (hi/lo);
//   old = atomicAdd(Vpart[i], r); second arriver runs diag+epilogue.

#define N_ATOMS 1024
#define L_DIM 64
#define CSCALE 2.8853900817779268f   // 2*log2(e)

typedef _Float16 f16x8 __attribute__((ext_vector_type(8)));
typedef __fp16  fp16x2 __attribute__((ext_vector_type(2)));
typedef float f32x4 __attribute__((ext_vector_type(4)));

__device__ __forceinline__ float tanh_fast(float x) {
    float e = __builtin_amdgcn_exp2f(x * CSCALE);
    float r = __builtin_amdgcn_rcpf(e + 1.0f);
    return fmaf(-2.0f, r, 1.0f);
}

// ---------------- Stage 1: prep ----------------
__global__ __launch_bounds__(256) void k_prep(const int* __restrict__ cat,
                                              const float* __restrict__ LM,
                                              const float* __restrict__ We1,
                                              const float* __restrict__ be1,
                                              const float* __restrict__ We2,
                                              const float* __restrict__ be2,
                                              float* __restrict__ H,
                                              float* __restrict__ preI,
                                              float* __restrict__ P3,
                                              float* __restrict__ Vpart,
                                              f16x8* __restrict__ bHg,
                                              f16x8* __restrict__ bLg,
                                              float* __restrict__ biasg,
                                              float* __restrict__ out) {
    int t = threadIdx.x;
    int sub = t >> 6, l = t & 63;
    int i = blockIdx.x * 4 + sub;
    if (blockIdx.x == 0 && t == 0) out[0] = 0.f;
    if (t < 4) Vpart[blockIdx.x * 4 + t] = 0.f;
    __shared__ float hrow[4][L_DIM];
    float hv = LM[cat[i] * L_DIM + l];
    hrow[sub][l] = hv;
    H[i * L_DIM + l] = hv;
    __syncthreads();
    float s1 = 0.f, s2 = 0.f;
#pragma unroll
    for (int m = 0; m < L_DIM; m++) {
        float h = hrow[sub][m];
        s1 = fmaf(h, We1[m * L_DIM + l], s1);
        s2 = fmaf(h, We1[(L_DIM + m) * L_DIM + l], s2);
    }
    preI[i * L_DIM + l] = s1 * CSCALE;
    // pack c*(prejb) into A-fragment order (verified R2/R4):
    int cc = i >> 4;
    int Ll = i & 15;
    int quad = (l >> 3) & 3;
    int L = quad * 16 + Ll;
    int g = ((l >> 5) << 1) | ((l >> 2) & 1);
    int e2 = l & 3;
    P3[cc * 1024 + g * 256 + L * 4 + e2] = (s2 + be1[l]) * CSCALE;

    // --- i-independent B-fragment + bias build (once, block 0; wave w <-> nt) ---
    if (blockIdx.x == 0) {
        int nt = t >> 6;          // 0..3
        int lane = t & 63;
        int q2 = lane >> 4, nl2 = lane & 15;
        float psum = 0.f;
#pragma unroll
        for (int kt = 0; kt < 2; kt++) {
            f16x8 hi8, lo8;
#pragma unroll
            for (int e = 0; e < 8; e++) {
                float x = We2[(kt * 32 + q2 * 8 + e) * L_DIM + nt * 16 + nl2];
                psum += x;
                float wp = -2.0f * CSCALE * x;
                _Float16 hi = (_Float16)wp;
                hi8[e] = hi;
                lo8[e] = (_Float16)(wp - (float)hi);
            }
            bHg[(kt * 4 + nt) * 64 + lane] = hi8;
            bLg[(kt * 4 + nt) * 64 + lane] = lo8;
        }
        psum += __shfl_xor(psum, 16);
        psum += __shfl_xor(psum, 32);
        biasg[lane * 4 + nt] = CSCALE * (be2[nt * 16 + nl2] + psum);
    }
}

// ---------------- Stage 2: fused main (grid 2048: i = bid>>1, half = bid&1) ----------------
__global__ __launch_bounds__(256) void k_main(const float* __restrict__ Z,
                                              const float* __restrict__ We1,
                                              const float* __restrict__ preI,
                                              const float* __restrict__ P3,
                                              const f16x8* __restrict__ bHg,
                                              const f16x8* __restrict__ bLg,
                                              const float* __restrict__ biasg,
                                              const float* __restrict__ H,
                                              const float* __restrict__ We2,
                                              const float* __restrict__ be2,
                                              const float* __restrict__ Wh1,
                                              const float* __restrict__ bh1,
                                              const float* __restrict__ Wh2,
                                              const float* __restrict__ bh2,
                                              const float* __restrict__ Wo,
                                              const float* __restrict__ bo,
                                              float* __restrict__ Vpart,
                                              float* __restrict__ out) {
    int bid = blockIdx.x;
    int i = bid >> 1, half = bid & 1;
    int t = threadIdx.x;
    int lane = t & 63;
    int wave = t >> 6;          // 0..3
    int nlo = lane & 15;
    int quad = lane >> 4;

    __shared__ float d2s[512];
    __shared__ float red[256];
    __shared__ f16x8 bLs[8 * 64];   // 8 KB
    __shared__ float dgt[L_DIM];
    __shared__ float hrow_s[L_DIM];
    __shared__ float hhs[L_DIM];
    __shared__ float RallS;
    __shared__ int   winflag;

    // d2 table for this i, this half of j
    float zi0 = Z[i * 3], zi1 = Z[i * 3 + 1], zi2 = Z[i * 3 + 2];
    for (int p = t; p < 512; p += 256) {
        int j = half * 512 + p;
        float a = zi0 - Z[j * 3], b = zi1 - Z[j * 3 + 1], c = zi2 - Z[j * 3 + 2];
        d2s[p] = a * a + b * b + c * c;
    }

    // per-lane constants
    f32x4 aiR[4], wzR[4];
#pragma unroll
    for (int g = 0; g < 4; g++) {
        int mb = ((g >> 1) << 5) + (quad << 3) + ((g & 1) << 2);
        aiR[g] = *(const f32x4*)(preI + i * L_DIM + mb);
        f32x4 wz = *(const f32x4*)(We1 + 2 * L_DIM * L_DIM + mb);
        wzR[g] = wz * CSCALE;
    }

    // B fragments from precomputed tables: hi to regs, lo to LDS (cooperative)
    f16x8 bH[4][2];
#pragma unroll
    for (int nt = 0; nt < 4; nt++) {
        bH[nt][0] = bHg[(0 * 4 + nt) * 64 + lane];
        bH[nt][1] = bHg[(1 * 4 + nt) * 64 + lane];
    }
#pragma unroll
    for (int idx = 0; idx < 2; idx++) {
        int e = wave + idx * 4;
        bLs[e * 64 + lane] = bLg[e * 64 + lane];
    }
    f32x4 bias4 = *(const f32x4*)(biasg + lane * 4);

    // 8 chunks of 16 j per wave; aiR folded into the p registers.
    const float* Pbase = P3 + (half * 32 + wave * 8) * 1024 + lane * 4;
    f32x4 p0 = *(const f32x4*)(Pbase + 0 * 256) + aiR[0];
    f32x4 p1 = *(const f32x4*)(Pbase + 1 * 256) + aiR[1];
    f32x4 p2 = *(const f32x4*)(Pbase + 2 * 256) + aiR[2];
    f32x4 p3 = *(const f32x4*)(Pbase + 3 * 256) + aiR[3];

    __syncthreads();

    f32x4 Vr4 = {0.f, 0.f, 0.f, 0.f};   // sum over this half's j,l of 1/(exp2(S')+1)
    for (int k = 0; k < 8; k++) {
        float d2 = d2s[(wave * 8 + k) * 16 + nlo];
        f32x4 d2v = {d2, d2, d2, d2};

        // A-frag: r = 1/(exp2(z)+1) per element
        f32x4 z0 = p0 + d2v * wzR[0];
        f32x4 z1 = p1 + d2v * wzR[1];
        f32x4 z2 = p2 + d2v * wzR[2];
        f32x4 z3 = p3 + d2v * wzR[3];
        f32x4 ex0, ex1, ex2, ex3;
#pragma unroll
        for (int e = 0; e < 4; e++) {
            ex0[e] = __builtin_amdgcn_exp2f(z0[e]);
            ex1[e] = __builtin_amdgcn_exp2f(z1[e]);
            ex2[e] = __builtin_amdgcn_exp2f(z2[e]);
            ex3[e] = __builtin_amdgcn_exp2f(z3[e]);
        }
        ex0 += 1.0f; ex1 += 1.0f; ex2 += 1.0f; ex3 += 1.0f;
        f32x4 r0, r1, r2, r3;
#pragma unroll
        for (int e = 0; e < 4; e++) {
            r0[e] = __builtin_amdgcn_rcpf(ex0[e]);
            r1[e] = __builtin_amdgcn_rcpf(ex1[e]);
            r2[e] = __builtin_amdgcn_rcpf(ex2[e]);
            r3[e] = __builtin_amdgcn_rcpf(ex3[e]);
        }
        union { f16x8 v; fp16x2 h2[4]; } u0, u1;
        u0.h2[0] = __builtin_amdgcn_cvt_pkrtz(r0[0], r0[1]);
        u0.h2[1] = __builtin_amdgcn_cvt_pkrtz(r0[2], r0[3]);
        u0.h2[2] = __builtin_amdgcn_cvt_pkrtz(r1[0], r1[1]);
        u0.h2[3] = __builtin_amdgcn_cvt_pkrtz(r1[2], r1[3]);
        u1.h2[0] = __builtin_amdgcn_cvt_pkrtz(r2[0], r2[1]);
        u1.h2[1] = __builtin_amdgcn_cvt_pkrtz(r2[2], r2[3]);
        u1.h2[2] = __builtin_amdgcn_cvt_pkrtz(r3[0], r3[1]);
        u1.h2[3] = __builtin_amdgcn_cvt_pkrtz(r3[2], r3[3]);
        f16x8 aH0 = u0.v, aH1 = u1.v;

        if (k < 7) {
            const float* nb = Pbase + (k + 1) * 1024;
            p0 = *(const f32x4*)(nb + 0 * 256) + aiR[0];
            p1 = *(const f32x4*)(nb + 1 * 256) + aiR[1];
            p2 = *(const f32x4*)(nb + 2 * 256) + aiR[2];
            p3 = *(const f32x4*)(nb + 3 * 256) + aiR[3];
        }

#pragma unroll
        for (int nt = 0; nt < 4; nt++) {
            f16x8 bl0 = bLs[(0 * 4 + nt) * 64 + lane];
            f16x8 bl1 = bLs[(1 * 4 + nt) * 64 + lane];
            f32x4 acc = {bias4[nt], bias4[nt], bias4[nt], bias4[nt]};
            acc = __builtin_amdgcn_mfma_f32_16x16x32_f16(aH0, bH[nt][0], acc, 0, 0, 0);
            acc = __builtin_amdgcn_mfma_f32_16x16x32_f16(aH0, bl0, acc, 0, 0, 0);
            acc = __builtin_amdgcn_mfma_f32_16x16x32_f16(aH1, bH[nt][1], acc, 0, 0, 0);
            acc = __builtin_amdgcn_mfma_f32_16x16x32_f16(aH1, bl1, acc, 0, 0, 0);
            f32x4 ev;
#pragma unroll
            for (int r4 = 0; r4 < 4; r4++) ev[r4] = __builtin_amdgcn_exp2f(acc[r4]);
            ev += 1.0f;
            f32x4 rv;
#pragma unroll
            for (int r4 = 0; r4 < 4; r4++) rv[r4] = __builtin_amdgcn_rcpf(ev[r4]);
            Vr4 += rv;
        }
    }

    red[t] = Vr4[0] + Vr4[1] + Vr4[2] + Vr4[3];
    __syncthreads();

    // partial reduce + return-value election (no fence, no counter):
    // each r is a sum of 32768 sigmoids in (0,1) — strictly positive, so
    // old==0.0f  <=>  we are the first arriver for atom i.
    if (t < 64) {
        float r = red[t] + red[t + 64] + red[t + 128] + red[t + 192];
#pragma unroll
        for (int o = 32; o > 0; o >>= 1) r += __shfl_xor(r, o);
        if (t == 0) {
            float old = atomicAdd(Vpart + i, r);
            winflag = (old != 0.0f);
            RallS = old + r;
        }
    }
    __syncthreads();

    if (winflag) {
        // ---- diagonal + epilogue for atom i (second-finishing block only) ----
        if (t < 64) {
            // diagonal h1 tanh (d2 = 0), m = t  — packed P3 index (verified R7 k_post)
            int cc = i >> 4, Ll = i & 15;
            int q2 = (t >> 3) & 3;
            int g = ((t >> 5) << 1) | ((t >> 2) & 1);
            float z = preI[i * L_DIM + t] + P3[cc * 1024 + g * 256 + (q2 * 16 + Ll) * 4 + (t & 3)];
            float rr = __builtin_amdgcn_rcpf(__builtin_amdgcn_exp2f(z) + 1.0f);
            dgt[t] = fmaf(-2.0f, rr, 1.0f);
            hrow_s[t] = H[i * L_DIM + t];
        }
        __syncthreads();
        if (t < 64) {
            float S = be2[t];
#pragma unroll
            for (int m = 0; m < L_DIM; m++) S = fmaf(dgt[m], We2[m * L_DIM + t], S);
            float rd = __builtin_amdgcn_rcpf(__builtin_amdgcn_exp2f(S * CSCALE) + 1.0f);
#pragma unroll
            for (int o = 32; o > 0; o >>= 1) rd += __shfl_xor(rd, o);
            float V = fmaf(-2.0f, RallS - rd, (float)(1023 * L_DIM));
            float s = 0.f;
#pragma unroll
            for (int m = 0; m < L_DIM; m++) s = fmaf(hrow_s[m], Wh1[m * L_DIM + t], s);
            s = fmaf(V, Wh1[L_DIM * L_DIM + t], s) + bh1[t];
            hhs[t] = tanh_fast(s);
        }
        __syncthreads();
        if (t < 64) {
            float s2 = 0.f;
#pragma unroll
            for (int m = 0; m < L_DIM; m++) s2 = fmaf(hhs[m], Wh2[m * L_DIM + t], s2);
            float nh = tanh_fast(s2 + bh2[t]);
            float w = nh * Wo[t];
#pragma unroll
            for (int o = 32; o > 0; o >>= 1) w += __shfl_down(w, o);
            if (t == 0) atomicAdd(out, w + (i == 0 ? bo[0] : 0.f));
        }
    }
}

extern "C" void kernel_launch(void* const* d_in, const int* in_sizes, int n_in,
                              void* d_out, int out_size, void* d_ws, size_t ws_size,
                              hipStream_t stream) {
    const int*   cat = (const int*)  d_in[0];
    const float* Z   = (const float*)d_in[1];
    const float* LM  = (const float*)d_in[2];
    const float* We1 = (const float*)d_in[3];
    const float* be1 = (const float*)d_in[4];
    const float* We2 = (const float*)d_in[5];
    const float* be2 = (const float*)d_in[6];
    const float* Wh1 = (const float*)d_in[7];
    const float* bh1 = (const float*)d_in[8];
    const float* Wh2 = (const float*)d_in[9];
    const float* bh2 = (const float*)d_in[10];
    const float* Wo  = (const float*)d_in[11];
    const float* bo  = (const float*)d_in[12];
    float* out = (float*)d_out;

    float* ws    = (float*)d_ws;
    float* H     = ws;                        // 1024*64
    float* preI  = H     + N_ATOMS * L_DIM;   // 1024*64 (c-prescaled)
    float* P3    = preI  + N_ATOMS * L_DIM;   // 1024*64 (packed, c-prescaled)
    float* Vpart = P3    + N_ATOMS * L_DIM;   // 1024
    float* biasg = Vpart + N_ATOMS;           // 256
    f16x8* bHg   = (f16x8*)(biasg + 256);     // 8 KB
    f16x8* bLg   = bHg + 8 * 64;              // 8 KB

    k_prep<<<N_ATOMS / 4, 256, 0, stream>>>(cat, LM, We1, be1, We2, be2,
                                            H, preI, P3, Vpart, bHg, bLg, biasg, out);
    k_main<<<N_ATOMS * 2, 256, 0, stream>>>(Z, We1, preI, P3, bHg, bLg, biasg,
                                            H, We2, be2, Wh1, bh1, Wh2, bh2, Wo, bo,
                                            Vpart, out);
}